// Round 17
// baseline (180.244 us; speedup 1.0000x reference)
//
#include <hip/hip_runtime.h>

#define MAXL 8
#define NC 81              // (MAXL+1)^2
#define NPAIR 1179648      // 3072*768/2
#define TOTW  2359296      // 3072*768
#define PI_F 3.14159265358979323846f
#define CO_BLOCKS 256      // k_coeff: known-good 55us config (round 9/12)

typedef __attribute__((ext_vector_type(8))) __bf16 bf16x8;
typedef __attribute__((ext_vector_type(4))) float f32x4;
typedef __attribute__((address_space(3))) void lds_void;
typedef const __attribute__((address_space(1))) void glb_void;

// ---------------- compile-time norm table ----------------
constexpr double cfact(int n){ double r=1.0; for(int i=2;i<=n;++i) r*=(double)i; return r; }
constexpr double csqrtd(double x){
  double r = (x > 1.0) ? x : 1.0;
  for (int i=0;i<200;++i) r = 0.5*(r + x/r);
  return r;
}
struct Norms { float v[NC]; };
constexpr Norms make_norms(){
  Norms t{};
  for (int l=0;l<=MAXL;++l)
    for (int m=-l;m<=l;++m){
      int am = m<0?-m:m;
      double nn = csqrtd((double)(2*l+1)*cfact(l-am)/cfact(l+am)/(4.0*3.14159265358979323846));
      t.v[l*l+l+m] = (float)nn;
    }
  return t;
}
__constant__ Norms g_norm = make_norms();

__device__ __forceinline__ float fast_atanh(float x){
  return 0.5f * __logf((1.0f + x) * __builtin_amdgcn_rcpf(1.0f - x));
}

// ---------------- pass 1: max |fused z| (+ gacc zeroing; no k_init needed) ----------------
// scaleBits uses SIGNED-int atomicMax: positive floats order correctly as ints, and the
// 0xAA poison (negative int) loses to any real value -> no pre-zero required, replay-safe.
__global__ __launch_bounds__(256) void k_max(const float* __restrict__ wfc,
    const float* __restrict__ wpr, int* __restrict__ scaleBits,
    double* __restrict__ gacc, float imp0, float imp1){
  const int mat = blockIdx.y;
  if (mat == 0 && blockIdx.x == 0 && threadIdx.x < 2*NC) gacc[threadIdx.x] = 0.0;
  const float2* w0 = (const float2*)(mat ? wpr : wfc);
  const float2* w1 = w0 + (TOTW/2);
  float vmax = 0.0f;
  for (int i = blockIdx.x*blockDim.x + threadIdx.x; i < NPAIR; i += gridDim.x*blockDim.x){
    float2 a = w0[i], b = w1[i];
    float re = fmaf(imp0, a.x, imp1*b.x);
    float im = fmaf(imp0, a.y, imp1*b.y);
    vmax = fmaxf(vmax, sqrtf(re*re + im*im));
  }
  for (int off=32; off; off>>=1) vmax = fmaxf(vmax, __shfl_down(vmax, off));
  __shared__ float red[4];
  int lane = threadIdx.x & 63, wv = threadIdx.x >> 6;
  if (lane == 0) red[wv] = vmax;
  __syncthreads();
  if (threadIdx.x == 0){
    float m = fmaxf(fmaxf(red[0], red[1]), fmaxf(red[2], red[3]));
    atomicMax(scaleBits + mat, (int)__float_as_uint(m));
  }
}

// ---------------- coeff reduction: 2-pt ILP (256,2) + fused x-gather prologue ----------------
// The gather is pure BW (31.5 MB) riding under this latency-bound kernel's idle memory pipe.
__global__ __launch_bounds__(256,2) void k_coeff(const float* __restrict__ wfc,
                                                 const float* __restrict__ wpr,
                                                 const unsigned* __restrict__ scaleBits,
                                                 double* __restrict__ gacc,
                                                 const float* __restrict__ x,
                                                 __bf16* __restrict__ A1){
  const int mat = blockIdx.y;

  // fused gather: even columns of x -> bf16 A1 (512 blocks total co-operate)
  {
    const int g0 = (mat*CO_BLOCKS + blockIdx.x)*256 + threadIdx.x;
    const int gs = 2*CO_BLOCKS*256;
    #pragma unroll 4
    for (int t = g0; t < 8192*384; t += gs){
      float2 v = ((const float2*)x)[t];
      A1[t] = (__bf16)v.x;
    }
  }

  const float2* w0 = (const float2*)(mat ? wpr : wfc);
  const float2* w1 = w0 + (TOTW/2);
  const float scale = __uint_as_float(scaleBits[mat]);
  const bool has = scale > 0.0f;
  const float inv_safe = 1.0f / (has ? scale : 1.0f);
  const float imp0 = (float)0.37754066879814546;
  const float imp1 = (float)0.62245933120185454;

  float acc[NC];
  #pragma unroll
  for (int v=0; v<NC; ++v) acc[v] = 0.0f;

  auto map1 = [&](int idx, float& X, float& c1, float& s1, float& st){
    float2 av = w0[idx], bv = w1[idx];
    float re = fmaf(imp0, av.x, imp1*bv.x);
    float im = fmaf(imp0, av.y, imp1*bv.y);
    float pr, pi_;
    if (has){
      float a = re*inv_safe, b = im*inv_safe;
      float e  = __expf(2.0f*a);
      float ie = __builtin_amdgcn_rcpf(e);
      float ch = 0.5f*(e + ie), sh = 0.5f*(e - ie);
      float s2b, c2b; __sincosf(2.0f*b, &s2b, &c2b);
      float inv_den = __builtin_amdgcn_rcpf(ch + c2b);
      pr  = sh*inv_den*0.95f;
      pi_ = s2b*inv_den*0.95f;
    } else { pr = re; pi_ = im; }
    float r2 = pr*pr + pi_*pi_;
    float inv_r = (r2 > 0.0f) ? __builtin_amdgcn_rsqf(r2) : 0.0f;
    c1 = (r2 > 0.0f) ? pr*inv_r : 1.0f;
    s1 = pi_*inv_r;
    float rr_ = r2*inv_r;
    float arg = fast_atanh(fminf(rr_, 0.99f)) * (PI_F/8.0f);
    __sincosf(arg, &st, &X);     // st = sin(arg) == sqrt(1-X^2), arg in [0,1.04]
  };

  const int T = CO_BLOCKS*256;
  for (int i = blockIdx.x*blockDim.x + threadIdx.x; i < NPAIR/2; i += T){
    float X0,c10,s10,st0, X1,c11,s11,st1;
    map1(i,           X0, c10, s10, st0);
    map1(i + NPAIR/2, X1, c11, s11, st1);

    float cm0=1.0f, sm0=0.0f, pm0=1.0f;
    float cm1=1.0f, sm1=0.0f, pm1=1.0f;
    float fact=1.0f;
    #pragma unroll
    for (int m=0; m<=MAXL; ++m){
      if (m > 0){
        float t0 = cm0*c10 - sm0*s10; sm0 = sm0*c10 + cm0*s10; cm0 = t0;
        float t1 = cm1*c11 - sm1*s11; sm1 = sm1*c11 + cm1*s11; cm1 = t1;
        pm0 = pm0 * (-fact*st0);
        pm1 = pm1 * (-fact*st1);
        fact += 2.0f;
      }
      float a1 = pm0, b1 = pm1;
      acc[m*m + 2*m] += a1*cm0 + b1*cm1;
      if (m > 0) acc[m*m] += a1*sm0 + b1*sm1;
      if (m < MAXL){
        float a0 = a1, b0 = b1;
        a1 = X0*(float)(2*m+1)*a0;
        b1 = X1*(float)(2*m+1)*b0;
        acc[(m+1)*(m+1) + (m+1) + m] += a1*cm0 + b1*cm1;
        if (m > 0) acc[(m+1)*(m+1) + 1] += a1*sm0 + b1*sm1;
        #pragma unroll
        for (int l=m+2; l<=MAXL; ++l){
          float an = ((float)(2*l-1)*X0*a1 - (float)(l+m-1)*a0) * (1.0f/(float)(l-m));
          a0 = a1; a1 = an;
          float bn = ((float)(2*l-1)*X1*b1 - (float)(l+m-1)*b0) * (1.0f/(float)(l-m));
          b0 = b1; b1 = bn;
          acc[l*l + l + m] += a1*cm0 + b1*cm1;
          if (m > 0) acc[l*l + l - m] += a1*sm0 + b1*sm1;
        }
      }
    }
  }

  __shared__ float redf[4][NC];
  int lane = threadIdx.x & 63, wv = threadIdx.x >> 6;
  #pragma unroll
  for (int v=0; v<NC; ++v){
    float d = acc[v];
    for (int off=32; off; off>>=1) d += __shfl_down(d, off);
    if (lane == 0) redf[wv][v] = d;
  }
  __syncthreads();
  for (int v = threadIdx.x; v < NC; v += blockDim.x){
    double s = (double)redf[0][v] + (double)redf[1][v] + (double)redf[2][v] + (double)redf[3][v];
    unsafeAtomicAdd(gacc + mat*NC + v, s);
  }
}

// ---------------- compress: parallel (81 threads) ----------------
__global__ __launch_bounds__(128) void k_compress(const double* __restrict__ gacc,
                                                  float* __restrict__ cfin){
  const int mat = blockIdx.x;
  const int v = threadIdx.x;
  __shared__ float mg[NC];
  __shared__ float smg2[NC];
  __shared__ int cnt_sh;

  float c = 0.0f, m = -1.0f;
  if (v < NC){
    double m_ = (double)g_norm.v[v] * gacc[mat*NC + v] / (double)NPAIR;
    c = (float)m_;
    m = fabsf(c);
    mg[v] = m;
  }
  if (v == 0) cnt_sh = 0;
  __syncthreads();

  int rank = 0;
  if (v < NC){
    #pragma unroll 1
    for (int u = 0; u < NC; ++u){
      float mu = mg[u];
      rank += (mu > m) || (mu == m && u < v);
    }
    smg2[rank] = m*m;
  }
  __syncthreads();

  float e_mine = 0.0f, tot = 0.0f;
  if (v < NC){
    float run = 0.0f;
    #pragma unroll 1
    for (int u = 0; u < NC; ++u){
      run += smg2[u];
      if (u == rank) e_mine = run;
    }
    tot = run;
    float den = fmaxf(tot, 1e-30f);
    if (tot > 0.0f && (e_mine / den <= 0.9999f)) atomicAdd(&cnt_sh, 1);
  }
  __syncthreads();

  if (v < NC){
    int kc = (tot > 0.0f) ? (cnt_sh + 1) : NC;
    if (kc < NC/2) kc = NC/2;   // 40
    float cv = (rank < kc) ? c : 0.0f;
    if (fabsf(cv) <= 1e-10f) cv = 0.0f;
    cfin[mat*NC + v] = cv;
  }
}

// ---------------- inverse transform -> compact bf16 B1 (1536x384), B2 (768x1536) ----------------
__global__ __launch_bounds__(256) void k_inverse(const float* __restrict__ cfin,
    const unsigned* __restrict__ scaleBits, __bf16* __restrict__ B1, __bf16* __restrict__ B2){
  __shared__ float cA[NC], cB[NC], sc[2];
  if (threadIdx.x < NC){ cA[threadIdx.x] = cfin[threadIdx.x]; cB[threadIdx.x] = cfin[NC + threadIdx.x]; }
  if (threadIdx.x < 2) sc[threadIdx.x] = __uint_as_float(scaleBits[threadIdx.x]);
  __syncthreads();
  int j = blockIdx.x*blockDim.x + threadIdx.x;
  if (j >= NPAIR) return;

  float jf = (float)j;
  float r = fminf((jf + 0.5f) / 1179648.0f * 0.95f, 0.95f);
  float theta = fmodf((6.28318530717958647692f * jf) * 0.618033988749f, 1.0f);
  float phi = theta;
  float X, sint;
  {
    float arg = fast_atanh(fminf(r, 0.99f)) * (PI_F/8.0f);
    __sincosf(arg, &sint, &X);
  }
  float s1, c1; __sincosf(phi, &s1, &c1);   // phi in [0,1)

  float ra = 0.0f, rb = 0.0f;
  float cm = 1.0f, sm = 0.0f, pmm = 1.0f, fact = 1.0f;

  auto emit = [&](int l, int m, float P){
    int ip = l*l + l + m;
    float y = g_norm.v[ip] * P;
    float yc = y*cm;
    ra += cA[ip]*yc; rb += cB[ip]*yc;
    if (m > 0){
      int in_ = l*l + l - m;
      float ys = y*sm;
      ra += cA[in_]*ys; rb += cB[in_]*ys;
    }
  };

  #pragma unroll
  for (int m=0; m<=MAXL; ++m){
    if (m > 0){
      float t = cm*c1 - sm*s1;
      sm = sm*c1 + cm*s1;
      cm = t;
      pmm = pmm * (-fact*sint);
      fact += 2.0f;
    }
    float p0 = pmm;
    emit(m, m, p0);
    if (m < MAXL){
      float p1 = X*(float)(2*m+1)*p0;
      emit(m+1, m, p1);
      #pragma unroll
      for (int l=m+2; l<=MAXL; ++l){
        float pn = ((float)(2*l-1)*X*p1 - (float)(l+m-1)*p0) * (1.0f/(float)(l-m));
        p0 = p1; p1 = pn;
        emit(l, m, p1);
      }
    }
  }

  float sA = sc[0], sB = sc[1];
  B2[j] = (__bf16)((sB > 0.0f) ? rb*sB : rb);
  int q = j / 768, rem = j - q*768;
  if (rem < 384)
    B1[q*384 + rem] = (__bf16)((sA > 0.0f) ? ra*sA : ra);
}

// ---------------- bf16 MFMA GEMM (NT), BK=32, double-buffered 2-phase prefetch ----------------
template<int ACT, int OUTBF, int MI, int NJ>
__global__ __launch_bounds__(256) void k_gemm_mfma(
    const __bf16* __restrict__ A, const __bf16* __restrict__ B,
    const float* __restrict__ bias, int bmul, int blen,
    float imp0, float imp1,
    __bf16* __restrict__ Hout, float* __restrict__ Fout,
    int N, int K)
{
  constexpr int BM = 2*MI*16, BN = 2*NJ*16;
  constexpr int ACH = BM/16, NCH = (BM+BN)/16;   // 16-row chunks (1KB each)
  static_assert(NCH % 4 == 0, "chunks must split across 4 waves");
  __shared__ __bf16 As[2][BM*32];
  __shared__ __bf16 Bs[2][BN*32];
  const int tid  = threadIdx.x;
  const int wave = tid >> 6, lane = tid & 63;
  const int wr = wave >> 1, wc = wave & 1;
  const int rr = lane & 15, kq = lane >> 4;
  const int sx = rr & 3;               // read-side swizzle key (row & 3)
  const int bm = blockIdx.y * BM, bn = blockIdx.x * BN;

  const int lrow  = lane >> 2;         // 0..15: row within 16-row chunk
  const int lslot = lane & 3;          // 0..3: physical 16B slot
  const int sslot = lslot ^ (lrow & 3);// pre-swizzled source slot
  const __bf16* Abase = A + (size_t)bm * K;
  const __bf16* Bbase = B + (size_t)bn * K;

  f32x4 acc[MI][NJ] = {};

  auto stage = [&](int buf, int k0){
    #pragma unroll
    for (int is = 0; is < NCH/4; ++is) {
      const int c = is * 4 + wave;     // wave-uniform chunk id
      if (c < ACH) {
        const __bf16* ga = Abase + (size_t)(c*16 + lrow) * K + (k0 + sslot*8);
        __builtin_amdgcn_global_load_lds((glb_void*)ga, (lds_void*)(&As[buf][c*512]), 16, 0, 0);
      } else {
        const int cb = c - ACH;
        const __bf16* gb = Bbase + (size_t)(cb*16 + lrow) * K + (k0 + sslot*8);
        __builtin_amdgcn_global_load_lds((glb_void*)gb, (lds_void*)(&Bs[buf][cb*512]), 16, 0, 0);
      }
    }
  };

  const int nt = K/32;
  stage(0, 0);
  __syncthreads();

  for (int t = 0; t < nt; ++t) {
    const int cur = t & 1;
    if (t + 1 < nt) stage(cur ^ 1, (t+1)*32);   // prefetch overlaps compute below

    bf16x8 af[MI], bfr[NJ];
    #pragma unroll
    for (int i=0;i<MI;++i){
      const int row = wr*MI*16 + i*16 + rr;
      af[i]  = *(const bf16x8*)&As[cur][row*32 + ((kq ^ sx) << 3)];
    }
    #pragma unroll
    for (int j=0;j<NJ;++j){
      const int row = wc*NJ*16 + j*16 + rr;
      bfr[j] = *(const bf16x8*)&Bs[cur][row*32 + ((kq ^ sx) << 3)];
    }
    #pragma unroll
    for (int i=0;i<MI;++i)
      #pragma unroll
      for (int j=0;j<NJ;++j)
        acc[i][j] = __builtin_amdgcn_mfma_f32_16x16x32_bf16(af[i], bfr[j], acc[i][j], 0, 0, 0);

    __syncthreads();   // publishes prefetch (vmcnt drain) + protects buffer swap
  }

  // epilogue: C/D layout col=lane&15, row=(lane>>4)*4+reg
  #pragma unroll
  for (int j=0;j<NJ;++j){
    const int col = bn + wc*NJ*16 + j*16 + rr;
    const float bb = imp0*bias[bmul*col] + imp1*bias[blen + bmul*col];
    #pragma unroll
    for (int i=0;i<MI;++i){
      const int row0 = bm + wr*MI*16 + i*16 + kq*4;
      #pragma unroll
      for (int t=0;t<4;++t){
        float v = acc[i][j][t] + bb;
        if (ACT) v = 0.5f*v*(1.0f + erff(v*0.70710678118654752440f));
        if (OUTBF) Hout[(size_t)(row0+t)*N + col] = (__bf16)v;
        else       Fout[(size_t)(row0+t)*N + col] = v;
      }
    }
  }
}

// ---------------- launch ----------------
extern "C" void kernel_launch(void* const* d_in, const int* in_sizes, int n_in,
                              void* d_out, int out_size, void* d_ws, size_t ws_size,
                              hipStream_t stream){
  const float* x   = (const float*)d_in[0];
  const float* wfc = (const float*)d_in[1];
  const float* wpr = (const float*)d_in[2];
  const float* bfc = (const float*)d_in[3];
  const float* bpr = (const float*)d_in[4];
  float* out = (float*)d_out;

  char* ws = (char*)d_ws;
  size_t off = 0;
  auto alloc = [&](size_t bytes){ void* p = ws + off; off = (off + bytes + 255) & ~(size_t)255; return p; };

  unsigned* scaleBits= (unsigned*)alloc(8);
  double* gacc       = (double*)  alloc(2*NC*sizeof(double));
  float* cfin        = (float*)   alloc(2*NC*sizeof(float));
  __bf16* B1         = (__bf16*)  alloc((size_t)1536*384*sizeof(__bf16));
  __bf16* B2         = (__bf16*)  alloc((size_t)768*1536*sizeof(__bf16));
  __bf16* A1         = (__bf16*)  alloc((size_t)8192*384*sizeof(__bf16));
  __bf16* H          = (__bf16*)  alloc((size_t)8192*1536*sizeof(__bf16));

  const float imp0 = (float)0.37754066879814546;   // softmax([0,0.5])
  const float imp1 = (float)0.62245933120185454;

  k_max<<<dim3(1024,2),256,0,stream>>>(wfc, wpr, (int*)scaleBits, gacc, imp0, imp1);
  k_coeff<<<dim3(CO_BLOCKS,2),256,0,stream>>>(wfc, wpr, scaleBits, gacc, x, A1);
  k_compress<<<2,128,0,stream>>>(gacc, cfin);
  k_inverse<<<4608,256,0,stream>>>(cfin, scaleBits, B1, B2);
  // GEMM1: H[8192,1536] = gelu(A1 . B1^T + bias_fc[2*col]), 128x128 tile, BK=32 dbuf
  k_gemm_mfma<1,1,4,4><<<dim3(12,64),256,0,stream>>>(A1, B1, bfc, 2, 3072, imp0, imp1, H, nullptr, 1536, 384);
  // GEMM2: out[8192,768] = H . B2^T + bias_proj[col], 128x64 tile, BK=32 dbuf, 768 blocks (3/CU exact)
  k_gemm_mfma<0,0,4,2><<<dim3(12,64),256,0,stream>>>(H, B2, bpr, 1, 768, imp0, imp1, nullptr, out, 768, 1536);
}

// Round 18
// 164.448 us; speedup vs baseline: 1.0961x; 1.0961x over previous
//
#include <hip/hip_runtime.h>

#define MAXL 8
#define NC 81              // (MAXL+1)^2
#define NPAIR 1179648      // 3072*768/2
#define TOTW  2359296      // 3072*768
#define PI_F 3.14159265358979323846f
#define CO_BLOCKS 256      // k_coeff: known-good 55us config (round 9/12)

typedef __attribute__((ext_vector_type(8))) __bf16 bf16x8;
typedef __attribute__((ext_vector_type(4))) float f32x4;
typedef __attribute__((address_space(3))) void lds_void;
typedef const __attribute__((address_space(1))) void glb_void;

// ---------------- compile-time norm table ----------------
constexpr double cfact(int n){ double r=1.0; for(int i=2;i<=n;++i) r*=(double)i; return r; }
constexpr double csqrtd(double x){
  double r = (x > 1.0) ? x : 1.0;
  for (int i=0;i<200;++i) r = 0.5*(r + x/r);
  return r;
}
struct Norms { float v[NC]; };
constexpr Norms make_norms(){
  Norms t{};
  for (int l=0;l<=MAXL;++l)
    for (int m=-l;m<=l;++m){
      int am = m<0?-m:m;
      double nn = csqrtd((double)(2*l+1)*cfact(l-am)/cfact(l+am)/(4.0*3.14159265358979323846));
      t.v[l*l+l+m] = (float)nn;
    }
  return t;
}
__constant__ Norms g_norm = make_norms();

__device__ __forceinline__ float fast_atanh(float x){
  return 0.5f * __logf((1.0f + x) * __builtin_amdgcn_rcpf(1.0f - x));
}

// ---------------- pass 1: max |fused z| (+ gacc zeroing; no k_init needed) ----------------
// scaleBits uses SIGNED-int atomicMax: positive floats order correctly as ints, and the
// 0xAA poison (negative int) loses to any real value -> no pre-zero required, replay-safe.
// 256 blocks/mat: keeps same-address atomics at 256/addr (G12 — 1024/mat regressed +15us, R16).
__global__ __launch_bounds__(256) void k_max(const float* __restrict__ wfc,
    const float* __restrict__ wpr, int* __restrict__ scaleBits,
    double* __restrict__ gacc, float imp0, float imp1){
  const int mat = blockIdx.y;
  if (mat == 0 && blockIdx.x == 0 && threadIdx.x < 2*NC) gacc[threadIdx.x] = 0.0;
  const float2* w0 = (const float2*)(mat ? wpr : wfc);
  const float2* w1 = w0 + (TOTW/2);
  float vmax = 0.0f;
  for (int i = blockIdx.x*blockDim.x + threadIdx.x; i < NPAIR; i += gridDim.x*blockDim.x){
    float2 a = w0[i], b = w1[i];
    float re = fmaf(imp0, a.x, imp1*b.x);
    float im = fmaf(imp0, a.y, imp1*b.y);
    vmax = fmaxf(vmax, sqrtf(re*re + im*im));
  }
  for (int off=32; off; off>>=1) vmax = fmaxf(vmax, __shfl_down(vmax, off));
  __shared__ float red[4];
  int lane = threadIdx.x & 63, wv = threadIdx.x >> 6;
  if (lane == 0) red[wv] = vmax;
  __syncthreads();
  if (threadIdx.x == 0){
    float m = fmaxf(fmaxf(red[0], red[1]), fmaxf(red[2], red[3]));
    atomicMax(scaleBits + mat, (int)__float_as_uint(m));
  }
}

// ---------------- coeff reduction: 2-pt ILP (256,2) + fused x-gather prologue ----------------
// The gather is pure BW (31.5 MB) riding under this latency-bound kernel's idle memory pipe.
__global__ __launch_bounds__(256,2) void k_coeff(const float* __restrict__ wfc,
                                                 const float* __restrict__ wpr,
                                                 const unsigned* __restrict__ scaleBits,
                                                 double* __restrict__ gacc,
                                                 const float* __restrict__ x,
                                                 __bf16* __restrict__ A1){
  const int mat = blockIdx.y;

  // fused gather: even columns of x -> bf16 A1 (512 blocks total co-operate)
  {
    const int g0 = (mat*CO_BLOCKS + blockIdx.x)*256 + threadIdx.x;
    const int gs = 2*CO_BLOCKS*256;
    #pragma unroll 4
    for (int t = g0; t < 8192*384; t += gs){
      float2 v = ((const float2*)x)[t];
      A1[t] = (__bf16)v.x;
    }
  }

  const float2* w0 = (const float2*)(mat ? wpr : wfc);
  const float2* w1 = w0 + (TOTW/2);
  const float scale = __uint_as_float(scaleBits[mat]);
  const bool has = scale > 0.0f;
  const float inv_safe = 1.0f / (has ? scale : 1.0f);
  const float imp0 = (float)0.37754066879814546;
  const float imp1 = (float)0.62245933120185454;

  float acc[NC];
  #pragma unroll
  for (int v=0; v<NC; ++v) acc[v] = 0.0f;

  auto map1 = [&](int idx, float& X, float& c1, float& s1, float& st){
    float2 av = w0[idx], bv = w1[idx];
    float re = fmaf(imp0, av.x, imp1*bv.x);
    float im = fmaf(imp0, av.y, imp1*bv.y);
    float pr, pi_;
    if (has){
      float a = re*inv_safe, b = im*inv_safe;
      float e  = __expf(2.0f*a);
      float ie = __builtin_amdgcn_rcpf(e);
      float ch = 0.5f*(e + ie), sh = 0.5f*(e - ie);
      float s2b, c2b; __sincosf(2.0f*b, &s2b, &c2b);
      float inv_den = __builtin_amdgcn_rcpf(ch + c2b);
      pr  = sh*inv_den*0.95f;
      pi_ = s2b*inv_den*0.95f;
    } else { pr = re; pi_ = im; }
    float r2 = pr*pr + pi_*pi_;
    float inv_r = (r2 > 0.0f) ? __builtin_amdgcn_rsqf(r2) : 0.0f;
    c1 = (r2 > 0.0f) ? pr*inv_r : 1.0f;
    s1 = pi_*inv_r;
    float rr_ = r2*inv_r;
    float arg = fast_atanh(fminf(rr_, 0.99f)) * (PI_F/8.0f);
    __sincosf(arg, &st, &X);     // st = sin(arg) == sqrt(1-X^2), arg in [0,1.04]
  };

  const int T = CO_BLOCKS*256;
  for (int i = blockIdx.x*blockDim.x + threadIdx.x; i < NPAIR/2; i += T){
    float X0,c10,s10,st0, X1,c11,s11,st1;
    map1(i,           X0, c10, s10, st0);
    map1(i + NPAIR/2, X1, c11, s11, st1);

    float cm0=1.0f, sm0=0.0f, pm0=1.0f;
    float cm1=1.0f, sm1=0.0f, pm1=1.0f;
    float fact=1.0f;
    #pragma unroll
    for (int m=0; m<=MAXL; ++m){
      if (m > 0){
        float t0 = cm0*c10 - sm0*s10; sm0 = sm0*c10 + cm0*s10; cm0 = t0;
        float t1 = cm1*c11 - sm1*s11; sm1 = sm1*c11 + cm1*s11; cm1 = t1;
        pm0 = pm0 * (-fact*st0);
        pm1 = pm1 * (-fact*st1);
        fact += 2.0f;
      }
      float a1 = pm0, b1 = pm1;
      acc[m*m + 2*m] += a1*cm0 + b1*cm1;
      if (m > 0) acc[m*m] += a1*sm0 + b1*sm1;
      if (m < MAXL){
        float a0 = a1, b0 = b1;
        a1 = X0*(float)(2*m+1)*a0;
        b1 = X1*(float)(2*m+1)*b0;
        acc[(m+1)*(m+1) + (m+1) + m] += a1*cm0 + b1*cm1;
        if (m > 0) acc[(m+1)*(m+1) + 1] += a1*sm0 + b1*sm1;
        #pragma unroll
        for (int l=m+2; l<=MAXL; ++l){
          float an = ((float)(2*l-1)*X0*a1 - (float)(l+m-1)*a0) * (1.0f/(float)(l-m));
          a0 = a1; a1 = an;
          float bn = ((float)(2*l-1)*X1*b1 - (float)(l+m-1)*b0) * (1.0f/(float)(l-m));
          b0 = b1; b1 = bn;
          acc[l*l + l + m] += a1*cm0 + b1*cm1;
          if (m > 0) acc[l*l + l - m] += a1*sm0 + b1*sm1;
        }
      }
    }
  }

  __shared__ float redf[4][NC];
  int lane = threadIdx.x & 63, wv = threadIdx.x >> 6;
  #pragma unroll
  for (int v=0; v<NC; ++v){
    float d = acc[v];
    for (int off=32; off; off>>=1) d += __shfl_down(d, off);
    if (lane == 0) redf[wv][v] = d;
  }
  __syncthreads();
  for (int v = threadIdx.x; v < NC; v += blockDim.x){
    double s = (double)redf[0][v] + (double)redf[1][v] + (double)redf[2][v] + (double)redf[3][v];
    unsafeAtomicAdd(gacc + mat*NC + v, s);
  }
}

// ---------------- compress: parallel (81 threads) ----------------
__global__ __launch_bounds__(128) void k_compress(const double* __restrict__ gacc,
                                                  float* __restrict__ cfin){
  const int mat = blockIdx.x;
  const int v = threadIdx.x;
  __shared__ float mg[NC];
  __shared__ float smg2[NC];
  __shared__ int cnt_sh;

  float c = 0.0f, m = -1.0f;
  if (v < NC){
    double m_ = (double)g_norm.v[v] * gacc[mat*NC + v] / (double)NPAIR;
    c = (float)m_;
    m = fabsf(c);
    mg[v] = m;
  }
  if (v == 0) cnt_sh = 0;
  __syncthreads();

  int rank = 0;
  if (v < NC){
    #pragma unroll 1
    for (int u = 0; u < NC; ++u){
      float mu = mg[u];
      rank += (mu > m) || (mu == m && u < v);
    }
    smg2[rank] = m*m;
  }
  __syncthreads();

  float e_mine = 0.0f, tot = 0.0f;
  if (v < NC){
    float run = 0.0f;
    #pragma unroll 1
    for (int u = 0; u < NC; ++u){
      run += smg2[u];
      if (u == rank) e_mine = run;
    }
    tot = run;
    float den = fmaxf(tot, 1e-30f);
    if (tot > 0.0f && (e_mine / den <= 0.9999f)) atomicAdd(&cnt_sh, 1);
  }
  __syncthreads();

  if (v < NC){
    int kc = (tot > 0.0f) ? (cnt_sh + 1) : NC;
    if (kc < NC/2) kc = NC/2;   // 40
    float cv = (rank < kc) ? c : 0.0f;
    if (fabsf(cv) <= 1e-10f) cv = 0.0f;
    cfin[mat*NC + v] = cv;
  }
}

// ---------------- inverse transform -> compact bf16 B1 (1536x384), B2 (768x1536) ----------------
__global__ __launch_bounds__(256) void k_inverse(const float* __restrict__ cfin,
    const unsigned* __restrict__ scaleBits, __bf16* __restrict__ B1, __bf16* __restrict__ B2){
  __shared__ float cA[NC], cB[NC], sc[2];
  if (threadIdx.x < NC){ cA[threadIdx.x] = cfin[threadIdx.x]; cB[threadIdx.x] = cfin[NC + threadIdx.x]; }
  if (threadIdx.x < 2) sc[threadIdx.x] = __uint_as_float(scaleBits[threadIdx.x]);
  __syncthreads();
  int j = blockIdx.x*blockDim.x + threadIdx.x;
  if (j >= NPAIR) return;

  float jf = (float)j;
  float r = fminf((jf + 0.5f) / 1179648.0f * 0.95f, 0.95f);
  float theta = fmodf((6.28318530717958647692f * jf) * 0.618033988749f, 1.0f);
  float phi = theta;
  float X, sint;
  {
    float arg = fast_atanh(fminf(r, 0.99f)) * (PI_F/8.0f);
    __sincosf(arg, &sint, &X);
  }
  float s1, c1; __sincosf(phi, &s1, &c1);   // phi in [0,1)

  float ra = 0.0f, rb = 0.0f;
  float cm = 1.0f, sm = 0.0f, pmm = 1.0f, fact = 1.0f;

  auto emit = [&](int l, int m, float P){
    int ip = l*l + l + m;
    float y = g_norm.v[ip] * P;
    float yc = y*cm;
    ra += cA[ip]*yc; rb += cB[ip]*yc;
    if (m > 0){
      int in_ = l*l + l - m;
      float ys = y*sm;
      ra += cA[in_]*ys; rb += cB[in_]*ys;
    }
  };

  #pragma unroll
  for (int m=0; m<=MAXL; ++m){
    if (m > 0){
      float t = cm*c1 - sm*s1;
      sm = sm*c1 + cm*s1;
      cm = t;
      pmm = pmm * (-fact*sint);
      fact += 2.0f;
    }
    float p0 = pmm;
    emit(m, m, p0);
    if (m < MAXL){
      float p1 = X*(float)(2*m+1)*p0;
      emit(m+1, m, p1);
      #pragma unroll
      for (int l=m+2; l<=MAXL; ++l){
        float pn = ((float)(2*l-1)*X*p1 - (float)(l+m-1)*p0) * (1.0f/(float)(l-m));
        p0 = p1; p1 = pn;
        emit(l, m, p1);
      }
    }
  }

  float sA = sc[0], sB = sc[1];
  B2[j] = (__bf16)((sB > 0.0f) ? rb*sB : rb);
  int q = j / 768, rem = j - q*768;
  if (rem < 384)
    B1[q*384 + rem] = (__bf16)((sA > 0.0f) ? ra*sA : ra);
}

// ---------------- bf16 MFMA GEMM (NT), BK=32, double-buffered 2-phase prefetch ----------------
template<int ACT, int OUTBF, int MI, int NJ>
__global__ __launch_bounds__(256) void k_gemm_mfma(
    const __bf16* __restrict__ A, const __bf16* __restrict__ B,
    const float* __restrict__ bias, int bmul, int blen,
    float imp0, float imp1,
    __bf16* __restrict__ Hout, float* __restrict__ Fout,
    int N, int K)
{
  constexpr int BM = 2*MI*16, BN = 2*NJ*16;
  constexpr int ACH = BM/16, NCH = (BM+BN)/16;   // 16-row chunks (1KB each)
  static_assert(NCH % 4 == 0, "chunks must split across 4 waves");
  __shared__ __bf16 As[2][BM*32];
  __shared__ __bf16 Bs[2][BN*32];
  const int tid  = threadIdx.x;
  const int wave = tid >> 6, lane = tid & 63;
  const int wr = wave >> 1, wc = wave & 1;
  const int rr = lane & 15, kq = lane >> 4;
  const int sx = rr & 3;               // read-side swizzle key (row & 3)
  const int bm = blockIdx.y * BM, bn = blockIdx.x * BN;

  const int lrow  = lane >> 2;         // 0..15: row within 16-row chunk
  const int lslot = lane & 3;          // 0..3: physical 16B slot
  const int sslot = lslot ^ (lrow & 3);// pre-swizzled source slot
  const __bf16* Abase = A + (size_t)bm * K;
  const __bf16* Bbase = B + (size_t)bn * K;

  f32x4 acc[MI][NJ] = {};

  auto stage = [&](int buf, int k0){
    #pragma unroll
    for (int is = 0; is < NCH/4; ++is) {
      const int c = is * 4 + wave;     // wave-uniform chunk id
      if (c < ACH) {
        const __bf16* ga = Abase + (size_t)(c*16 + lrow) * K + (k0 + sslot*8);
        __builtin_amdgcn_global_load_lds((glb_void*)ga, (lds_void*)(&As[buf][c*512]), 16, 0, 0);
      } else {
        const int cb = c - ACH;
        const __bf16* gb = Bbase + (size_t)(cb*16 + lrow) * K + (k0 + sslot*8);
        __builtin_amdgcn_global_load_lds((glb_void*)gb, (lds_void*)(&Bs[buf][cb*512]), 16, 0, 0);
      }
    }
  };

  const int nt = K/32;
  stage(0, 0);
  __syncthreads();

  for (int t = 0; t < nt; ++t) {
    const int cur = t & 1;
    if (t + 1 < nt) stage(cur ^ 1, (t+1)*32);   // prefetch overlaps compute below

    bf16x8 af[MI], bfr[NJ];
    #pragma unroll
    for (int i=0;i<MI;++i){
      const int row = wr*MI*16 + i*16 + rr;
      af[i]  = *(const bf16x8*)&As[cur][row*32 + ((kq ^ sx) << 3)];
    }
    #pragma unroll
    for (int j=0;j<NJ;++j){
      const int row = wc*NJ*16 + j*16 + rr;
      bfr[j] = *(const bf16x8*)&Bs[cur][row*32 + ((kq ^ sx) << 3)];
    }
    #pragma unroll
    for (int i=0;i<MI;++i)
      #pragma unroll
      for (int j=0;j<NJ;++j)
        acc[i][j] = __builtin_amdgcn_mfma_f32_16x16x32_bf16(af[i], bfr[j], acc[i][j], 0, 0, 0);

    __syncthreads();   // publishes prefetch (vmcnt drain) + protects buffer swap
  }

  // epilogue: C/D layout col=lane&15, row=(lane>>4)*4+reg
  #pragma unroll
  for (int j=0;j<NJ;++j){
    const int col = bn + wc*NJ*16 + j*16 + rr;
    const float bb = imp0*bias[bmul*col] + imp1*bias[blen + bmul*col];
    #pragma unroll
    for (int i=0;i<MI;++i){
      const int row0 = bm + wr*MI*16 + i*16 + kq*4;
      #pragma unroll
      for (int t=0;t<4;++t){
        float v = acc[i][j][t] + bb;
        if (ACT) v = 0.5f*v*(1.0f + erff(v*0.70710678118654752440f));
        if (OUTBF) Hout[(size_t)(row0+t)*N + col] = (__bf16)v;
        else       Fout[(size_t)(row0+t)*N + col] = v;
      }
    }
  }
}

// ---------------- launch ----------------
extern "C" void kernel_launch(void* const* d_in, const int* in_sizes, int n_in,
                              void* d_out, int out_size, void* d_ws, size_t ws_size,
                              hipStream_t stream){
  const float* x   = (const float*)d_in[0];
  const float* wfc = (const float*)d_in[1];
  const float* wpr = (const float*)d_in[2];
  const float* bfc = (const float*)d_in[3];
  const float* bpr = (const float*)d_in[4];
  float* out = (float*)d_out;

  char* ws = (char*)d_ws;
  size_t off = 0;
  auto alloc = [&](size_t bytes){ void* p = ws + off; off = (off + bytes + 255) & ~(size_t)255; return p; };

  unsigned* scaleBits= (unsigned*)alloc(8);
  double* gacc       = (double*)  alloc(2*NC*sizeof(double));
  float* cfin        = (float*)   alloc(2*NC*sizeof(float));
  __bf16* B1         = (__bf16*)  alloc((size_t)1536*384*sizeof(__bf16));
  __bf16* B2         = (__bf16*)  alloc((size_t)768*1536*sizeof(__bf16));
  __bf16* A1         = (__bf16*)  alloc((size_t)8192*384*sizeof(__bf16));
  __bf16* H          = (__bf16*)  alloc((size_t)8192*1536*sizeof(__bf16));

  const float imp0 = (float)0.37754066879814546;   // softmax([0,0.5])
  const float imp1 = (float)0.62245933120185454;

  k_max<<<dim3(256,2),256,0,stream>>>(wfc, wpr, (int*)scaleBits, gacc, imp0, imp1);
  k_coeff<<<dim3(CO_BLOCKS,2),256,0,stream>>>(wfc, wpr, scaleBits, gacc, x, A1);
  k_compress<<<2,128,0,stream>>>(gacc, cfin);
  k_inverse<<<4608,256,0,stream>>>(cfin, scaleBits, B1, B2);
  // GEMM1: H[8192,1536] = gelu(A1 . B1^T + bias_fc[2*col]), 128x128 tile, BK=32 dbuf
  k_gemm_mfma<1,1,4,4><<<dim3(12,64),256,0,stream>>>(A1, B1, bfc, 2, 3072, imp0, imp1, H, nullptr, 1536, 384);
  // GEMM2: out[8192,768] = H . B2^T + bias_proj[col], 128x128 tile, BK=32 dbuf
  k_gemm_mfma<0,0,4,4><<<dim3(6,64),256,0,stream>>>(H, B2, bpr, 1, 768, imp0, imp1, nullptr, out, 768, 1536);
}